// Round 4
// baseline (185.781 us; speedup 1.0000x reference)
//
#include <hip/hip_runtime.h>

#define N_NODES 100000
#define N_EDGES 1250000
#define D 64
#define NPB 256                  // nodes per coarse bucket (dst >> 8)
#define NB  391                  // ceil(N_NODES / NPB)
#define NPAD2 (NB * NPB)         // 100096
#define PTHREADS 512
#define EPT 4                    // edges per thread in place (was 8 -> more blocks, 2.4/CU)
#define EPB (PTHREADS * EPT)     // 2048 edges per block
#define NBLK ((N_EDGES + EPB - 1) / EPB)   // 611
#define CAP  4096                // static per-bucket capacity (mean 3197, +15 sigma)
#define CAPPAD 1792              // extra capacity for pad-to-8 (256*7)
#define CAPP (CAP + CAPPAD)      // 5888: per-bucket stride in ssp
#define DUMMY N_NODES            // featW[DUMMY] is a zero row
#define HP 68                    // LDS leading-dim pad (16B-aligned float4 rows)

// ---------------- init: gcursor[b] = b*CAP ----------------
__global__ void init_kernel(int* __restrict__ gcursor) {
    int i = blockIdx.x * 256 + threadIdx.x;
    if (i < NB) gcursor[i] = i * CAP;
}

// ---------------- place: local counting sort, wave-shfl scan, ascending emission ----------------
__global__ __launch_bounds__(PTHREADS) void place_kernel(const int* __restrict__ src,
                                                         const int* __restrict__ dst,
                                                         int* __restrict__ gcursor,
                                                         unsigned int* __restrict__ packed) {
    __shared__ int h[512];
    __shared__ int wtot[4];
    __shared__ int lstart[NB];
    __shared__ int gbase[NB];
    __shared__ int lcur[NB];
    __shared__ unsigned sortedv[EPB];
    __shared__ unsigned short binof[EPB];
    int t = threadIdx.x;
    h[t] = 0;
    __syncthreads();

    int base = blockIdx.x * EPB;
    int d[EPT], s[EPT];
    #pragma unroll
    for (int i = 0; i < EPT; ++i) {
        int e = base + t + i * PTHREADS;
        if (e < N_EDGES) {
            d[i] = dst[e]; s[i] = src[e];
            atomicAdd(&h[d[i] >> 8], 1);
        } else d[i] = -1;
    }
    __syncthreads();

    // inclusive scan of pair-sums over t<256: 4 wave-local shfl scans + combine
    int a0 = 0, a1 = 0, x = 0;
    if (t < 256) {
        a0 = h[2 * t]; a1 = h[2 * t + 1];
        x = a0 + a1;
        int lane = t & 63;
        #pragma unroll
        for (int off = 1; off < 64; off <<= 1) {
            int y = __shfl_up(x, off, 64);
            if (lane >= off) x += y;
        }
        if (lane == 63) wtot[t >> 6] = x;
    }
    __syncthreads();
    if (t == 0) {
        int s0 = 0;
        #pragma unroll
        for (int i = 0; i < 4; ++i) { int v = wtot[i]; wtot[i] = s0; s0 += v; }
    }
    __syncthreads();
    if (t < 256) {
        int pinc = x + wtot[t >> 6];
        int pexc = pinc - a0 - a1;
        if (2 * t < NB) {
            lstart[2 * t] = pexc;
            lcur[2 * t] = pexc;
            gbase[2 * t] = a0 ? atomicAdd(&gcursor[2 * t], a0) : 0;
        }
        if (2 * t + 1 < NB) {
            lstart[2 * t + 1] = pexc + a0;
            lcur[2 * t + 1] = pexc + a0;
            gbase[2 * t + 1] = a1 ? atomicAdd(&gcursor[2 * t + 1], a1) : 0;
        }
    }
    __syncthreads();

    #pragma unroll
    for (int i = 0; i < EPT; ++i) {
        if (d[i] >= 0) {
            int b = d[i] >> 8;
            int pos = atomicAdd(&lcur[b], 1);
            sortedv[pos] = ((unsigned)s[i] << 8) | (unsigned)(d[i] & 255);
            binof[pos] = (unsigned short)b;
        }
    }
    __syncthreads();

    int cnt = min(EPB, N_EDGES - base);
    for (int k = t; k < cnt; k += PTHREADS) {
        int b = binof[k];
        int gp = gbase[b] + (k - lstart[b]);
        if (gp < (b + 1) * CAP) packed[gp] = sortedv[k];
    }
}

// ---------------- refine + fused featW: padded CSR + norm + bf16(norm*(feat@W^T)) ----------------
__global__ __launch_bounds__(1024) void refine_featw_kernel(const unsigned int* __restrict__ packed,
                                                            const int* __restrict__ gcursor,
                                                            int* __restrict__ ssp,
                                                            int* __restrict__ pbeg,
                                                            int* __restrict__ pdega,
                                                            float* __restrict__ norm,
                                                            const float* __restrict__ feat,
                                                            const float* __restrict__ weight,
                                                            unsigned short* __restrict__ featW) {
    __shared__ int h[NPB];
    __shared__ int cur[NPB];
    __shared__ int wtot[4];
    __shared__ float normf[NPB];
    __shared__ float Wt[D * HP];      // 17408 B
    __shared__ float Hc[4][D * HP];   // 69632 B; total ~90 KB
    int b = blockIdx.x, t = threadIdx.x;
    int beg = b * CAP;
    int end = min(gcursor[b], (b + 1) * CAP);
    if (t < NPB) h[t] = 0;
    // stage W^T early (no dependence on histogram)
    for (int i = t; i < D * D; i += 1024) {
        int c = i & 63, dd = i >> 6;
        Wt[c * HP + dd] = weight[dd * D + c];
    }
    __syncthreads();
    for (int j = beg + t; j < end; j += 1024)
        atomicAdd(&h[packed[j] & 255], 1);
    __syncthreads();

    int deg = 0, pdeg = 0, x = 0;
    if (t < NPB) {
        deg = h[t];
        pdeg = (deg + 7) & ~7;
        x = pdeg;
        int lane = t & 63;
        #pragma unroll
        for (int off = 1; off < 64; off <<= 1) {
            int y = __shfl_up(x, off, 64);
            if (lane >= off) x += y;
        }
        if (lane == 63) wtot[t >> 6] = x;
    }
    __syncthreads();
    if (t == 0) {
        int s0 = 0;
        #pragma unroll
        for (int i = 0; i < 4; ++i) { int v = wtot[i]; wtot[i] = s0; s0 += v; }
    }
    __syncthreads();
    int pb = 0;
    if (t < NPB) {
        int inc = x + wtot[t >> 6];
        int exc = inc - pdeg;
        pb = b * CAPP + exc;
        cur[t] = pb;
        int n = b * NPB + t;
        pbeg[n] = pb;
        pdega[n] = pdeg;
        float nv = rsqrtf((float)(deg < 1 ? 1 : deg));
        norm[n] = nv;
        normf[t] = nv;
    }
    __syncthreads();
    for (int j = beg + t; j < end; j += 1024) {
        unsigned p = packed[j];
        int pos = atomicAdd(&cur[p & 255], 1);
        ssp[pos] = (int)(p >> 8);
    }
    __syncthreads();
    if (t < NPB) {
        int fend = pb + pdeg;
        for (int k = cur[t]; k < fend; ++k) ssp[k] = DUMMY;
    }

    // ---- fused featW: 4 parallel 64-node tiles, 256 threads each ----
    int g = t >> 8, tt = t & 255;
    int nb = b * NPB + g * 64;
    for (int idx = tt; idx < 64 * 16; idx += 256) {
        int nl = idx >> 4, q = idx & 15;
        int n = nb + nl;
        float4 v = make_float4(0.f, 0.f, 0.f, 0.f);
        float nn = 0.f;
        if (n < N_NODES) {
            v = ((const float4*)feat)[(size_t)n * 16 + q];
            nn = normf[g * 64 + nl];
        }
        Hc[g][(q * 4 + 0) * HP + nl] = v.x * nn;
        Hc[g][(q * 4 + 1) * HP + nl] = v.y * nn;
        Hc[g][(q * 4 + 2) * HP + nl] = v.z * nn;
        Hc[g][(q * 4 + 3) * HP + nl] = v.w * nn;
    }
    __syncthreads();

    int tx = tt & 15, ty = tt >> 4;
    float acc[4][4] = {};
    #pragma unroll 8
    for (int k = 0; k < D; ++k) {
        float4 a = *(const float4*)&Hc[g][k * HP + ty * 4];
        float4 bb = *(const float4*)&Wt[k * HP + tx * 4];
        acc[0][0] += a.x * bb.x; acc[0][1] += a.x * bb.y; acc[0][2] += a.x * bb.z; acc[0][3] += a.x * bb.w;
        acc[1][0] += a.y * bb.x; acc[1][1] += a.y * bb.y; acc[1][2] += a.y * bb.z; acc[1][3] += a.y * bb.w;
        acc[2][0] += a.z * bb.x; acc[2][1] += a.z * bb.y; acc[2][2] += a.z * bb.z; acc[2][3] += a.z * bb.w;
        acc[3][0] += a.w * bb.x; acc[3][1] += a.w * bb.y; acc[3][2] += a.w * bb.z; acc[3][3] += a.w * bb.w;
    }
    auto cvt = [](float v) -> unsigned {
        unsigned u = __float_as_uint(v);
        return (u + 0x7fff + ((u >> 16) & 1)) >> 16;
    };
    #pragma unroll
    for (int i = 0; i < 4; ++i) {
        int n = nb + ty * 4 + i;      // < NPAD2; rows >= N_NODES get exact zeros
        uint2 r;
        r.x = cvt(acc[i][0]) | (cvt(acc[i][1]) << 16);
        r.y = cvt(acc[i][2]) | (cvt(acc[i][3]) << 16);
        *(uint2*)&featW[(size_t)n * D + tx * 4] = r;
    }
}

// ---------------- gather_out: pure CSR gather -> *norm[dst] + bias -> out (verbatim r3) ----------------
#define ACC_EDGE(ACC, J) do {                                         \
        int s_ = ssp[(J)];                                            \
        uint2 r_ = *(const uint2*)&featW[(size_t)s_ * D + m * 4];     \
        ACC.x += __uint_as_float(r_.x << 16);                         \
        ACC.y += __uint_as_float(r_.x & 0xffff0000u);                 \
        ACC.z += __uint_as_float(r_.y << 16);                         \
        ACC.w += __uint_as_float(r_.y & 0xffff0000u);                 \
    } while (0)
#define ACC4(ACC, J) { ACC_EDGE(ACC, (J) + q); ACC_EDGE(ACC, (J) + 4 + q); \
                       ACC_EDGE(ACC, (J) + 8 + q); ACC_EDGE(ACC, (J) + 12 + q); }
#define ACC2(ACC, J) { ACC_EDGE(ACC, (J) + q); ACC_EDGE(ACC, (J) + 4 + q); }

__global__ __launch_bounds__(512) void gather_out_kernel(const unsigned short* __restrict__ featW,
                                                         const int* __restrict__ ssp,
                                                         const int* __restrict__ pbeg,
                                                         const int* __restrict__ pdega,
                                                         const float* __restrict__ norm,
                                                         const float* __restrict__ bias,
                                                         float* __restrict__ out) {
    int tid = threadIdx.x;
    int base = blockIdx.x * 32;          // 8 waves x 4 nodes
    int w = tid >> 6;
    int lane = tid & 63;
    int q = lane >> 4, m = lane & 15;
    float4 bv = ((const float4*)bias)[m];

    #pragma unroll
    for (int pr = 0; pr < 2; ++pr) {
        int nA = base + w * 4 + pr * 2;
        int nB = nA + 1;
        int begA = pbeg[nA], endA = begA + pdega[nA];
        int begB = pbeg[nB], endB = begB + pdega[nB];
        float4 aA = make_float4(0.f, 0.f, 0.f, 0.f);
        float4 aB = make_float4(0.f, 0.f, 0.f, 0.f);
        int jA = begA, jB = begB;
        while (jA + 16 <= endA && jB + 16 <= endB) {   // 8 row-loads in flight
            ACC4(aA, jA); ACC4(aB, jB);
            jA += 16; jB += 16;
        }
        for (; jA + 16 <= endA; jA += 16) ACC4(aA, jA);
        for (; jB + 16 <= endB; jB += 16) ACC4(aB, jB);
        if (jA < endA) ACC2(aA, jA);                    // exactly 8 remain
        if (jB < endB) ACC2(aB, jB);

        #pragma unroll
        for (int mask = 16; mask <= 32; mask <<= 1) {
            aA.x += __shfl_xor(aA.x, mask); aA.y += __shfl_xor(aA.y, mask);
            aA.z += __shfl_xor(aA.z, mask); aA.w += __shfl_xor(aA.w, mask);
            aB.x += __shfl_xor(aB.x, mask); aB.y += __shfl_xor(aB.y, mask);
            aB.z += __shfl_xor(aB.z, mask); aB.w += __shfl_xor(aB.w, mask);
        }
        float nnA = norm[nA], nnB = norm[nB];
        if (q == 0 && nA < N_NODES) {
            *(float4*)&out[(size_t)nA * D + m * 4] =
                make_float4(aA.x * nnA + bv.x, aA.y * nnA + bv.y,
                            aA.z * nnA + bv.z, aA.w * nnA + bv.w);
        }
        if (q == 1 && nB < N_NODES) {
            *(float4*)&out[(size_t)nB * D + m * 4] =
                make_float4(aB.x * nnB + bv.x, aB.y * nnB + bv.y,
                            aB.z * nnB + bv.z, aB.w * nnB + bv.w);
        }
    }
}

extern "C" void kernel_launch(void* const* d_in, const int* in_sizes, int n_in,
                              void* d_out, int out_size, void* d_ws, size_t ws_size,
                              hipStream_t stream) {
    const float* feat   = (const float*)d_in[0];
    const int*   src    = (const int*)d_in[1];
    const int*   dst    = (const int*)d_in[2];
    const float* weight = (const float*)d_in[3];
    const float* bias   = (const float*)d_in[4];
    float* out = (float*)d_out;

    // workspace layout (4-byte units); high water ~30 MB
    int* w = (int*)d_ws;
    int*      gcursor = w;                                   // [NB]
    int*      pbeg    = gcursor + NB;                        // [NPAD2]
    int*      pdega   = pbeg + NPAD2;                        // [NPAD2]
    float*    norm    = (float*)(pdega + NPAD2);             // [NPAD2]
    int*      ssp     = (int*)(norm + NPAD2);                // [NB*CAPP]
    unsigned* packed  = (unsigned*)(ssp + (size_t)NB * CAPP);// [NB*CAP]
    size_t featW_off = (size_t)NB + 3 * (size_t)NPAD2 + (size_t)NB * CAPP + (size_t)NB * CAP;
    featW_off = (featW_off + 3) & ~(size_t)3;                // 16B-align
    unsigned short* featW = (unsigned short*)(w + featW_off);// [NPAD2*D] bf16

    init_kernel        <<<2, 256, 0, stream>>>(gcursor);
    place_kernel       <<<NBLK, PTHREADS, 0, stream>>>(src, dst, gcursor, packed);
    refine_featw_kernel<<<NB, 1024, 0, stream>>>(packed, gcursor, ssp, pbeg, pdega, norm,
                                                 feat, weight, featW);
    gather_out_kernel  <<<(NPAD2 + 31) / 32, 512, 0, stream>>>(featW, ssp, pbeg, pdega, norm,
                                                               bias, out);
}

// Round 7
// 181.895 us; speedup vs baseline: 1.0214x; 1.0214x over previous
//
#include <hip/hip_runtime.h>

#define N_NODES 100000
#define N_EDGES 1250000
#define D 64
#define NPB 256                  // nodes per coarse bucket (dst >> 8)
#define NB  391                  // ceil(N_NODES / NPB)
#define NPAD2 (NB * NPB)         // 100096
#define PTHREADS 512
#define EPT 4                    // edges per thread in place -> 611 blocks, ~2.4/CU
#define EPB (PTHREADS * EPT)     // 2048 edges per block
#define NBLK ((N_EDGES + EPB - 1) / EPB)   // 611
#define CAP  4096                // static per-bucket capacity (mean 3197, +15 sigma)
#define CAPPAD 1792              // extra capacity for pad-to-8 (256*7)
#define CAPP (CAP + CAPPAD)      // 5888: per-bucket stride in ssp
#define DUMMY N_NODES            // featW[DUMMY] is a zero row
#define HP 68                    // LDS leading-dim pad (16B-aligned float4 rows)

// ---------------- init: gcursor[b] = b*CAP ----------------
__global__ void init_kernel(int* __restrict__ gcursor) {
    int i = blockIdx.x * 256 + threadIdx.x;
    if (i < NB) gcursor[i] = i * CAP;
}

// ---------------- place: local counting sort, wave-shfl scan, ascending emission ----------------
__global__ __launch_bounds__(PTHREADS) void place_kernel(const int* __restrict__ src,
                                                         const int* __restrict__ dst,
                                                         int* __restrict__ gcursor,
                                                         unsigned int* __restrict__ packed) {
    __shared__ int h[512];
    __shared__ int wtot[4];
    __shared__ int lstart[NB];
    __shared__ int gbase[NB];
    __shared__ int lcur[NB];
    __shared__ unsigned sortedv[EPB];
    __shared__ unsigned short binof[EPB];
    int t = threadIdx.x;
    h[t] = 0;
    __syncthreads();

    int base = blockIdx.x * EPB;
    int d[EPT], s[EPT];
    #pragma unroll
    for (int i = 0; i < EPT; ++i) {
        int e = base + t + i * PTHREADS;
        if (e < N_EDGES) {
            d[i] = dst[e]; s[i] = src[e];
            atomicAdd(&h[d[i] >> 8], 1);
        } else d[i] = -1;
    }
    __syncthreads();

    // inclusive scan of pair-sums over t<256: 4 wave-local shfl scans + combine
    int a0 = 0, a1 = 0, x = 0;
    if (t < 256) {
        a0 = h[2 * t]; a1 = h[2 * t + 1];
        x = a0 + a1;
        int lane = t & 63;
        #pragma unroll
        for (int off = 1; off < 64; off <<= 1) {
            int y = __shfl_up(x, off, 64);
            if (lane >= off) x += y;
        }
        if (lane == 63) wtot[t >> 6] = x;
    }
    __syncthreads();
    if (t == 0) {
        int s0 = 0;
        #pragma unroll
        for (int i = 0; i < 4; ++i) { int v = wtot[i]; wtot[i] = s0; s0 += v; }
    }
    __syncthreads();
    if (t < 256) {
        int pinc = x + wtot[t >> 6];
        int pexc = pinc - a0 - a1;
        int b0 = 2 * t, b1 = 2 * t + 1;
        if (b0 < NB) {
            lstart[b0] = pexc;
            lcur[b0] = pexc;
            gbase[b0] = a0 ? atomicAdd(&gcursor[b0], a0) : 0;
        }
        if (b1 < NB) {
            lstart[b1] = pexc + a0;
            lcur[b1] = pexc + a0;
            gbase[b1] = a1 ? atomicAdd(&gcursor[b1], a1) : 0;
        }
    }
    __syncthreads();

    #pragma unroll
    for (int i = 0; i < EPT; ++i) {
        if (d[i] >= 0) {
            int b = d[i] >> 8;
            int pos = atomicAdd(&lcur[b], 1);
            sortedv[pos] = ((unsigned)s[i] << 8) | (unsigned)(d[i] & 255);
            binof[pos] = (unsigned short)b;
        }
    }
    __syncthreads();

    int cnt = min(EPB, N_EDGES - base);
    for (int k = t; k < cnt; k += PTHREADS) {
        int b = binof[k];
        int gp = gbase[b] + (k - lstart[b]);
        if (gp < (b + 1) * CAP) packed[gp] = sortedv[k];
    }
}

// ---------------- refine: padded CSR + norm (wave-shfl scan) ----------------
__global__ __launch_bounds__(1024) void refine_kernel(const unsigned int* __restrict__ packed,
                                                      const int* __restrict__ gcursor,
                                                      int* __restrict__ ssp,
                                                      int* __restrict__ pbeg,
                                                      int* __restrict__ pdega,
                                                      float* __restrict__ norm) {
    __shared__ int h[NPB];
    __shared__ int cur[NPB];
    __shared__ int wtot[4];
    int b = blockIdx.x, t = threadIdx.x;
    int beg = b * CAP;
    int end = min(gcursor[b], (b + 1) * CAP);
    if (t < NPB) h[t] = 0;
    __syncthreads();
    for (int j = beg + t; j < end; j += 1024)
        atomicAdd(&h[packed[j] & 255], 1);
    __syncthreads();

    int deg = 0, pdeg = 0, x = 0;
    if (t < NPB) {
        deg = h[t];
        pdeg = (deg + 7) & ~7;
        x = pdeg;
        int lane = t & 63;
        #pragma unroll
        for (int off = 1; off < 64; off <<= 1) {
            int y = __shfl_up(x, off, 64);
            if (lane >= off) x += y;
        }
        if (lane == 63) wtot[t >> 6] = x;
    }
    __syncthreads();
    if (t == 0) {
        int s0 = 0;
        #pragma unroll
        for (int i = 0; i < 4; ++i) { int v = wtot[i]; wtot[i] = s0; s0 += v; }
    }
    __syncthreads();
    int pb = 0;
    if (t < NPB) {
        int inc = x + wtot[t >> 6];
        int exc = inc - pdeg;
        pb = b * CAPP + exc;
        cur[t] = pb;
        int n = b * NPB + t;
        pbeg[n] = pb;
        pdega[n] = pdeg;
        norm[n] = rsqrtf((float)(deg < 1 ? 1 : deg));
    }
    __syncthreads();
    for (int j = beg + t; j < end; j += 1024) {
        unsigned p = packed[j];
        int pos = atomicAdd(&cur[p & 255], 1);
        ssp[pos] = (int)(p >> 8);
    }
    __syncthreads();
    if (t < NPB) {
        int fend = pb + pdeg;
        for (int k = cur[t]; k < fend; ++k) ssp[k] = DUMMY;
    }
}

// ---------------- featw: featW[n] = bf16(norm[n] * (feat[n] @ W^T)), zeros past N_NODES ----------------
__global__ __launch_bounds__(256) void featw_kernel(const float* __restrict__ feat,
                                                    const float* __restrict__ norm,
                                                    const float* __restrict__ weight,
                                                    unsigned short* __restrict__ featW) {
    __shared__ float Hcol[D * HP];   // Hcol[k][n_local] = feat[n][k]*norm[n]
    __shared__ float Wt[D * HP];     // Wt[k][d]
    int tid = threadIdx.x;
    int base = blockIdx.x * 64;

    #pragma unroll
    for (int i = tid; i < D * D; i += 256) {
        int c = i & 63, dd = i >> 6;
        Wt[c * HP + dd] = weight[dd * D + c];
    }
    #pragma unroll
    for (int idx = tid; idx < 64 * 16; idx += 256) {
        int nl = idx >> 4, q = idx & 15;
        int n = base + nl;
        float4 v = make_float4(0.f, 0.f, 0.f, 0.f);
        float nn = 0.f;
        if (n < N_NODES) {
            v = ((const float4*)feat)[(size_t)n * 16 + q];
            nn = norm[n];
        }
        Hcol[(q * 4 + 0) * HP + nl] = v.x * nn;
        Hcol[(q * 4 + 1) * HP + nl] = v.y * nn;
        Hcol[(q * 4 + 2) * HP + nl] = v.z * nn;
        Hcol[(q * 4 + 3) * HP + nl] = v.w * nn;
    }
    __syncthreads();

    int tx = tid & 15, ty = tid >> 4;
    float acc[4][4] = {};
    #pragma unroll 8
    for (int k = 0; k < D; ++k) {
        float4 a = *(const float4*)&Hcol[k * HP + ty * 4];
        float4 b = *(const float4*)&Wt[k * HP + tx * 4];
        acc[0][0] += a.x * b.x; acc[0][1] += a.x * b.y; acc[0][2] += a.x * b.z; acc[0][3] += a.x * b.w;
        acc[1][0] += a.y * b.x; acc[1][1] += a.y * b.y; acc[1][2] += a.y * b.z; acc[1][3] += a.y * b.w;
        acc[2][0] += a.z * b.x; acc[2][1] += a.z * b.y; acc[2][2] += a.z * b.z; acc[2][3] += a.z * b.w;
        acc[3][0] += a.w * b.x; acc[3][1] += a.w * b.y; acc[3][2] += a.w * b.z; acc[3][3] += a.w * b.w;
    }
    auto cvt = [](float x) -> unsigned {
        unsigned u = __float_as_uint(x);
        return (u + 0x7fff + ((u >> 16) & 1)) >> 16;
    };
    #pragma unroll
    for (int i = 0; i < 4; ++i) {
        int n = base + ty * 4 + i;    // always < NPAD2; rows >= N_NODES get exact zeros
        uint2 r;
        r.x = cvt(acc[i][0]) | (cvt(acc[i][1]) << 16);
        r.y = cvt(acc[i][2]) | (cvt(acc[i][3]) << 16);
        *(uint2*)&featW[(size_t)n * D + tx * 4] = r;
    }
}

// ---------------- gather_out: pure CSR gather -> *norm[dst] + bias -> out (verbatim r3) ----------------
#define ACC_EDGE(ACC, J) do {                                         \
        int s_ = ssp[(J)];                                            \
        uint2 r_ = *(const uint2*)&featW[(size_t)s_ * D + m * 4];     \
        ACC.x += __uint_as_float(r_.x << 16);                         \
        ACC.y += __uint_as_float(r_.x & 0xffff0000u);                 \
        ACC.z += __uint_as_float(r_.y << 16);                         \
        ACC.w += __uint_as_float(r_.y & 0xffff0000u);                 \
    } while (0)
#define ACC4(ACC, J) { ACC_EDGE(ACC, (J) + q); ACC_EDGE(ACC, (J) + 4 + q); \
                       ACC_EDGE(ACC, (J) + 8 + q); ACC_EDGE(ACC, (J) + 12 + q); }
#define ACC2(ACC, J) { ACC_EDGE(ACC, (J) + q); ACC_EDGE(ACC, (J) + 4 + q); }

__global__ __launch_bounds__(512) void gather_out_kernel(const unsigned short* __restrict__ featW,
                                                         const int* __restrict__ ssp,
                                                         const int* __restrict__ pbeg,
                                                         const int* __restrict__ pdega,
                                                         const float* __restrict__ norm,
                                                         const float* __restrict__ bias,
                                                         float* __restrict__ out) {
    int tid = threadIdx.x;
    int base = blockIdx.x * 32;          // 8 waves x 4 nodes
    int w = tid >> 6;
    int lane = tid & 63;
    int q = lane >> 4, m = lane & 15;
    float4 bv = ((const float4*)bias)[m];

    #pragma unroll
    for (int pr = 0; pr < 2; ++pr) {
        int nA = base + w * 4 + pr * 2;
        int nB = nA + 1;
        int begA = pbeg[nA], endA = begA + pdega[nA];
        int begB = pbeg[nB], endB = begB + pdega[nB];
        float4 aA = make_float4(0.f, 0.f, 0.f, 0.f);
        float4 aB = make_float4(0.f, 0.f, 0.f, 0.f);
        int jA = begA, jB = begB;
        while (jA + 16 <= endA && jB + 16 <= endB) {   // 8 row-loads in flight
            ACC4(aA, jA); ACC4(aB, jB);
            jA += 16; jB += 16;
        }
        for (; jA + 16 <= endA; jA += 16) ACC4(aA, jA);
        for (; jB + 16 <= endB; jB += 16) ACC4(aB, jB);
        if (jA < endA) ACC2(aA, jA);                    // exactly 8 remain
        if (jB < endB) ACC2(aB, jB);

        #pragma unroll
        for (int mask = 16; mask <= 32; mask <<= 1) {
            aA.x += __shfl_xor(aA.x, mask); aA.y += __shfl_xor(aA.y, mask);
            aA.z += __shfl_xor(aA.z, mask); aA.w += __shfl_xor(aA.w, mask);
            aB.x += __shfl_xor(aB.x, mask); aB.y += __shfl_xor(aB.y, mask);
            aB.z += __shfl_xor(aB.z, mask); aB.w += __shfl_xor(aB.w, mask);
        }
        float nnA = norm[nA], nnB = norm[nB];
        if (q == 0 && nA < N_NODES) {
            *(float4*)&out[(size_t)nA * D + m * 4] =
                make_float4(aA.x * nnA + bv.x, aA.y * nnA + bv.y,
                            aA.z * nnA + bv.z, aA.w * nnA + bv.w);
        }
        if (q == 1 && nB < N_NODES) {
            *(float4*)&out[(size_t)nB * D + m * 4] =
                make_float4(aB.x * nnB + bv.x, aB.y * nnB + bv.y,
                            aB.z * nnB + bv.z, aB.w * nnB + bv.w);
        }
    }
}

extern "C" void kernel_launch(void* const* d_in, const int* in_sizes, int n_in,
                              void* d_out, int out_size, void* d_ws, size_t ws_size,
                              hipStream_t stream) {
    const float* feat   = (const float*)d_in[0];
    const int*   src    = (const int*)d_in[1];
    const int*   dst    = (const int*)d_in[2];
    const float* weight = (const float*)d_in[3];
    const float* bias   = (const float*)d_in[4];
    float* out = (float*)d_out;

    // workspace layout (4-byte units); high water ~30 MB
    int* w = (int*)d_ws;
    int*      gcursor = w;                                   // [NB]
    int*      pbeg    = gcursor + NB;                        // [NPAD2]
    int*      pdega   = pbeg + NPAD2;                        // [NPAD2]
    float*    norm    = (float*)(pdega + NPAD2);             // [NPAD2]
    int*      ssp     = (int*)(norm + NPAD2);                // [NB*CAPP]
    unsigned* packed  = (unsigned*)(ssp + (size_t)NB * CAPP);// [NB*CAP]
    size_t featW_off = (size_t)NB + 3 * (size_t)NPAD2 + (size_t)NB * CAPP + (size_t)NB * CAP;
    featW_off = (featW_off + 3) & ~(size_t)3;                // 16B-align
    unsigned short* featW = (unsigned short*)(w + featW_off);// [NPAD2*D] bf16

    init_kernel      <<<2, 256, 0, stream>>>(gcursor);
    place_kernel     <<<NBLK, PTHREADS, 0, stream>>>(src, dst, gcursor, packed);
    refine_kernel    <<<NB, 1024, 0, stream>>>(packed, gcursor, ssp, pbeg, pdega, norm);
    featw_kernel     <<<(NPAD2 + 63) / 64, 256, 0, stream>>>(feat, norm, weight, featW);
    gather_out_kernel<<<(NPAD2 + 31) / 32, 512, 0, stream>>>(featW, ssp, pbeg, pdega, norm,
                                                             bias, out);
}

// Round 8
// 174.734 us; speedup vs baseline: 1.0632x; 1.0410x over previous
//
#include <hip/hip_runtime.h>

#define N_NODES 100000
#define N_EDGES 1250000
#define D 64
#define NPB 256                  // nodes per coarse bucket (dst >> 8)
#define NB  391                  // ceil(N_NODES / NPB)
#define NPAD2 (NB * NPB)         // 100096
#define PTHREADS 512
#define EPT 8                    // edges per thread in place (measured best: r0/r3 vs r4/r7)
#define EPB (PTHREADS * EPT)     // 4096 edges per block
#define NBLK ((N_EDGES + EPB - 1) / EPB)   // 306
#define CAP  4096                // static per-bucket capacity (mean 3197, +15 sigma)
#define CAPPAD 1792              // extra capacity for pad-to-8 (256*7)
#define CAPP (CAP + CAPPAD)      // 5888: per-bucket stride in ssp
#define DUMMY N_NODES            // featW[DUMMY] is a zero row
#define HP 68                    // LDS leading-dim pad (16B-aligned float4 rows)

// ---------------- init: gcursor[b] = b*CAP ----------------
__global__ void init_kernel(int* __restrict__ gcursor) {
    int i = blockIdx.x * 256 + threadIdx.x;
    if (i < NB) gcursor[i] = i * CAP;
}

// ---------------- place: local counting sort, wave-shfl scan, ascending emission ----------------
__global__ __launch_bounds__(PTHREADS) void place_kernel(const int* __restrict__ src,
                                                         const int* __restrict__ dst,
                                                         int* __restrict__ gcursor,
                                                         unsigned int* __restrict__ packed) {
    __shared__ int h[512];
    __shared__ int wtot[4];
    __shared__ int lstart[NB];
    __shared__ int gbase[NB];
    __shared__ int lcur[NB];
    __shared__ unsigned sortedv[EPB];
    __shared__ unsigned short binof[EPB];
    int t = threadIdx.x;
    h[t] = 0;
    __syncthreads();

    int base = blockIdx.x * EPB;
    int d[EPT], s[EPT];
    #pragma unroll
    for (int i = 0; i < EPT; ++i) {
        int e = base + t + i * PTHREADS;
        if (e < N_EDGES) {
            d[i] = dst[e]; s[i] = src[e];
            atomicAdd(&h[d[i] >> 8], 1);
        } else d[i] = -1;
    }
    __syncthreads();

    // inclusive scan of pair-sums over t<256: 4 wave-local shfl scans + combine
    int a0 = 0, a1 = 0, x = 0;
    if (t < 256) {
        a0 = h[2 * t]; a1 = h[2 * t + 1];
        x = a0 + a1;
        int lane = t & 63;
        #pragma unroll
        for (int off = 1; off < 64; off <<= 1) {
            int y = __shfl_up(x, off, 64);
            if (lane >= off) x += y;
        }
        if (lane == 63) wtot[t >> 6] = x;
    }
    __syncthreads();
    if (t == 0) {
        int s0 = 0;
        #pragma unroll
        for (int i = 0; i < 4; ++i) { int v = wtot[i]; wtot[i] = s0; s0 += v; }
    }
    __syncthreads();
    if (t < 256) {
        int pinc = x + wtot[t >> 6];
        int pexc = pinc - a0 - a1;
        int b0 = 2 * t, b1 = 2 * t + 1;
        if (b0 < NB) {
            lstart[b0] = pexc;
            lcur[b0] = pexc;
            gbase[b0] = a0 ? atomicAdd(&gcursor[b0], a0) : 0;
        }
        if (b1 < NB) {
            lstart[b1] = pexc + a0;
            lcur[b1] = pexc + a0;
            gbase[b1] = a1 ? atomicAdd(&gcursor[b1], a1) : 0;
        }
    }
    __syncthreads();

    #pragma unroll
    for (int i = 0; i < EPT; ++i) {
        if (d[i] >= 0) {
            int b = d[i] >> 8;
            int pos = atomicAdd(&lcur[b], 1);
            sortedv[pos] = ((unsigned)s[i] << 8) | (unsigned)(d[i] & 255);
            binof[pos] = (unsigned short)b;
        }
    }
    __syncthreads();

    int cnt = min(EPB, N_EDGES - base);
    for (int k = t; k < cnt; k += PTHREADS) {
        int b = binof[k];
        int gp = gbase[b] + (k - lstart[b]);
        if (gp < (b + 1) * CAP) packed[gp] = sortedv[k];
    }
}

// ---------------- refine: padded CSR + norm (wave-shfl scan) ----------------
__global__ __launch_bounds__(1024) void refine_kernel(const unsigned int* __restrict__ packed,
                                                      const int* __restrict__ gcursor,
                                                      int* __restrict__ ssp,
                                                      int* __restrict__ pbeg,
                                                      int* __restrict__ pdega,
                                                      float* __restrict__ norm) {
    __shared__ int h[NPB];
    __shared__ int cur[NPB];
    __shared__ int wtot[4];
    int b = blockIdx.x, t = threadIdx.x;
    int beg = b * CAP;
    int end = min(gcursor[b], (b + 1) * CAP);
    if (t < NPB) h[t] = 0;
    __syncthreads();
    for (int j = beg + t; j < end; j += 1024)
        atomicAdd(&h[packed[j] & 255], 1);
    __syncthreads();

    int deg = 0, pdeg = 0, x = 0;
    if (t < NPB) {
        deg = h[t];
        pdeg = (deg + 7) & ~7;
        x = pdeg;
        int lane = t & 63;
        #pragma unroll
        for (int off = 1; off < 64; off <<= 1) {
            int y = __shfl_up(x, off, 64);
            if (lane >= off) x += y;
        }
        if (lane == 63) wtot[t >> 6] = x;
    }
    __syncthreads();
    if (t == 0) {
        int s0 = 0;
        #pragma unroll
        for (int i = 0; i < 4; ++i) { int v = wtot[i]; wtot[i] = s0; s0 += v; }
    }
    __syncthreads();
    int pb = 0;
    if (t < NPB) {
        int inc = x + wtot[t >> 6];
        int exc = inc - pdeg;
        pb = b * CAPP + exc;
        cur[t] = pb;
        int n = b * NPB + t;
        pbeg[n] = pb;
        pdega[n] = pdeg;
        norm[n] = rsqrtf((float)(deg < 1 ? 1 : deg));
    }
    __syncthreads();
    for (int j = beg + t; j < end; j += 1024) {
        unsigned p = packed[j];
        int pos = atomicAdd(&cur[p & 255], 1);
        ssp[pos] = (int)(p >> 8);
    }
    __syncthreads();
    if (t < NPB) {
        int fend = pb + pdeg;
        for (int k = cur[t]; k < fend; ++k) ssp[k] = DUMMY;
    }
}

// ---------------- featw: featW[n] = bf16(norm[n] * (feat[n] @ W^T)), zeros past N_NODES ----------------
__global__ __launch_bounds__(256) void featw_kernel(const float* __restrict__ feat,
                                                    const float* __restrict__ norm,
                                                    const float* __restrict__ weight,
                                                    unsigned short* __restrict__ featW) {
    __shared__ float Hcol[D * HP];   // Hcol[k][n_local] = feat[n][k]*norm[n]
    __shared__ float Wt[D * HP];     // Wt[k][d]
    int tid = threadIdx.x;
    int base = blockIdx.x * 64;

    #pragma unroll
    for (int i = tid; i < D * D; i += 256) {
        int c = i & 63, dd = i >> 6;
        Wt[c * HP + dd] = weight[dd * D + c];
    }
    #pragma unroll
    for (int idx = tid; idx < 64 * 16; idx += 256) {
        int nl = idx >> 4, q = idx & 15;
        int n = base + nl;
        float4 v = make_float4(0.f, 0.f, 0.f, 0.f);
        float nn = 0.f;
        if (n < N_NODES) {
            v = ((const float4*)feat)[(size_t)n * 16 + q];
            nn = norm[n];
        }
        Hcol[(q * 4 + 0) * HP + nl] = v.x * nn;
        Hcol[(q * 4 + 1) * HP + nl] = v.y * nn;
        Hcol[(q * 4 + 2) * HP + nl] = v.z * nn;
        Hcol[(q * 4 + 3) * HP + nl] = v.w * nn;
    }
    __syncthreads();

    int tx = tid & 15, ty = tid >> 4;
    float acc[4][4] = {};
    #pragma unroll 8
    for (int k = 0; k < D; ++k) {
        float4 a = *(const float4*)&Hcol[k * HP + ty * 4];
        float4 b = *(const float4*)&Wt[k * HP + tx * 4];
        acc[0][0] += a.x * b.x; acc[0][1] += a.x * b.y; acc[0][2] += a.x * b.z; acc[0][3] += a.x * b.w;
        acc[1][0] += a.y * b.x; acc[1][1] += a.y * b.y; acc[1][2] += a.y * b.z; acc[1][3] += a.y * b.w;
        acc[2][0] += a.z * b.x; acc[2][1] += a.z * b.y; acc[2][2] += a.z * b.z; acc[2][3] += a.z * b.w;
        acc[3][0] += a.w * b.x; acc[3][1] += a.w * b.y; acc[3][2] += a.w * b.z; acc[3][3] += a.w * b.w;
    }
    auto cvt = [](float x) -> unsigned {
        unsigned u = __float_as_uint(x);
        return (u + 0x7fff + ((u >> 16) & 1)) >> 16;
    };
    #pragma unroll
    for (int i = 0; i < 4; ++i) {
        int n = base + ty * 4 + i;    // always < NPAD2; rows >= N_NODES get exact zeros
        uint2 r;
        r.x = cvt(acc[i][0]) | (cvt(acc[i][1]) << 16);
        r.y = cvt(acc[i][2]) | (cvt(acc[i][3]) << 16);
        *(uint2*)&featW[(size_t)n * D + tx * 4] = r;
    }
}

// ---------------- gather_out: 4-node interleaved CSR gather -> *norm[dst] + bias -> out ----------------
#define ACC_EDGE(ACC, J) do {                                         \
        int s_ = ssp[(J)];                                            \
        uint2 r_ = *(const uint2*)&featW[(size_t)s_ * D + m * 4];     \
        ACC.x += __uint_as_float(r_.x << 16);                         \
        ACC.y += __uint_as_float(r_.x & 0xffff0000u);                 \
        ACC.z += __uint_as_float(r_.y << 16);                         \
        ACC.w += __uint_as_float(r_.y & 0xffff0000u);                 \
    } while (0)
#define ACC4(ACC, J) { ACC_EDGE(ACC, (J) + q); ACC_EDGE(ACC, (J) + 4 + q); \
                       ACC_EDGE(ACC, (J) + 8 + q); ACC_EDGE(ACC, (J) + 12 + q); }
#define ACC2(ACC, J) { ACC_EDGE(ACC, (J) + q); ACC_EDGE(ACC, (J) + 4 + q); }

__global__ __launch_bounds__(512) void gather_out_kernel(const unsigned short* __restrict__ featW,
                                                         const int* __restrict__ ssp,
                                                         const int* __restrict__ pbeg,
                                                         const int* __restrict__ pdega,
                                                         const float* __restrict__ norm,
                                                         const float* __restrict__ bias,
                                                         float* __restrict__ out) {
    int tid = threadIdx.x;
    int base = blockIdx.x * 32;          // 8 waves x 4 nodes
    int w = tid >> 6;
    int lane = tid & 63;
    int q = lane >> 4, m = lane & 15;
    float4 bv = ((const float4*)bias)[m];

    int n0 = base + w * 4;
    int g0 = pbeg[n0 + 0], e0 = g0 + pdega[n0 + 0];
    int g1 = pbeg[n0 + 1], e1 = g1 + pdega[n0 + 1];
    int g2 = pbeg[n0 + 2], e2 = g2 + pdega[n0 + 2];
    int g3 = pbeg[n0 + 3], e3 = g3 + pdega[n0 + 3];
    float4 a0 = make_float4(0.f, 0.f, 0.f, 0.f);
    float4 a1 = make_float4(0.f, 0.f, 0.f, 0.f);
    float4 a2 = make_float4(0.f, 0.f, 0.f, 0.f);
    float4 a3 = make_float4(0.f, 0.f, 0.f, 0.f);
    int j0 = g0, j1 = g1, j2 = g2, j3 = g3;

    // main loop: 16 row-loads in flight (4 nodes x 4 edges/lane-group)
    while (j0 + 16 <= e0 && j1 + 16 <= e1 && j2 + 16 <= e2 && j3 + 16 <= e3) {
        ACC4(a0, j0); ACC4(a1, j1); ACC4(a2, j2); ACC4(a3, j3);
        j0 += 16; j1 += 16; j2 += 16; j3 += 16;
    }
    // per-node drains (pdeg is a multiple of 8 -> remainder is a run of 16s plus at most one 8)
    for (; j0 + 16 <= e0; j0 += 16) ACC4(a0, j0);
    if (j0 < e0) ACC2(a0, j0);
    for (; j1 + 16 <= e1; j1 += 16) ACC4(a1, j1);
    if (j1 < e1) ACC2(a1, j1);
    for (; j2 + 16 <= e2; j2 += 16) ACC4(a2, j2);
    if (j2 < e2) ACC2(a2, j2);
    for (; j3 + 16 <= e3; j3 += 16) ACC4(a3, j3);
    if (j3 < e3) ACC2(a3, j3);

    // reduce across q (lanes ^16, ^32): afterwards every lane holds full sums
    #pragma unroll
    for (int mask = 16; mask <= 32; mask <<= 1) {
        a0.x += __shfl_xor(a0.x, mask); a0.y += __shfl_xor(a0.y, mask);
        a0.z += __shfl_xor(a0.z, mask); a0.w += __shfl_xor(a0.w, mask);
        a1.x += __shfl_xor(a1.x, mask); a1.y += __shfl_xor(a1.y, mask);
        a1.z += __shfl_xor(a1.z, mask); a1.w += __shfl_xor(a1.w, mask);
        a2.x += __shfl_xor(a2.x, mask); a2.y += __shfl_xor(a2.y, mask);
        a2.z += __shfl_xor(a2.z, mask); a2.w += __shfl_xor(a2.w, mask);
        a3.x += __shfl_xor(a3.x, mask); a3.y += __shfl_xor(a3.y, mask);
        a3.z += __shfl_xor(a3.z, mask); a3.w += __shfl_xor(a3.w, mask);
    }

    // q-group writes node n0+q: lane (q,m) stores column group m
    int n = n0 + q;
    float4 av = (q == 0) ? a0 : (q == 1) ? a1 : (q == 2) ? a2 : a3;
    if (n < N_NODES) {
        float nn = norm[n];
        *(float4*)&out[(size_t)n * D + m * 4] =
            make_float4(av.x * nn + bv.x, av.y * nn + bv.y,
                        av.z * nn + bv.z, av.w * nn + bv.w);
    }
}

extern "C" void kernel_launch(void* const* d_in, const int* in_sizes, int n_in,
                              void* d_out, int out_size, void* d_ws, size_t ws_size,
                              hipStream_t stream) {
    const float* feat   = (const float*)d_in[0];
    const int*   src    = (const int*)d_in[1];
    const int*   dst    = (const int*)d_in[2];
    const float* weight = (const float*)d_in[3];
    const float* bias   = (const float*)d_in[4];
    float* out = (float*)d_out;

    // workspace layout (4-byte units); high water ~30 MB
    int* w = (int*)d_ws;
    int*      gcursor = w;                                   // [NB]
    int*      pbeg    = gcursor + NB;                        // [NPAD2]
    int*      pdega   = pbeg + NPAD2;                        // [NPAD2]
    float*    norm    = (float*)(pdega + NPAD2);             // [NPAD2]
    int*      ssp     = (int*)(norm + NPAD2);                // [NB*CAPP]
    unsigned* packed  = (unsigned*)(ssp + (size_t)NB * CAPP);// [NB*CAP]
    size_t featW_off = (size_t)NB + 3 * (size_t)NPAD2 + (size_t)NB * CAPP + (size_t)NB * CAP;
    featW_off = (featW_off + 3) & ~(size_t)3;                // 16B-align
    unsigned short* featW = (unsigned short*)(w + featW_off);// [NPAD2*D] bf16

    init_kernel      <<<2, 256, 0, stream>>>(gcursor);
    place_kernel     <<<NBLK, PTHREADS, 0, stream>>>(src, dst, gcursor, packed);
    refine_kernel    <<<NB, 1024, 0, stream>>>(packed, gcursor, ssp, pbeg, pdega, norm);
    featw_kernel     <<<(NPAD2 + 63) / 64, 256, 0, stream>>>(feat, norm, weight, featW);
    gather_out_kernel<<<(NPAD2 + 31) / 32, 512, 0, stream>>>(featW, ssp, pbeg, pdega, norm,
                                                             bias, out);
}

// Round 9
// 168.643 us; speedup vs baseline: 1.1016x; 1.0361x over previous
//
#include <hip/hip_runtime.h>

#define N_NODES 100000
#define N_EDGES 1250000
#define D 64
#define NPB 256                  // nodes per coarse bucket (dst >> 8)
#define NB  391                  // ceil(N_NODES / NPB)
#define NPAD2 (NB * NPB)         // 100096
#define PTHREADS 512
#define EPT 10                   // edges per thread -> 245 blocks <= 256 CUs: ONE scheduling round
#define EPB (PTHREADS * EPT)     // 5120 edges per block
#define NBLK ((N_EDGES + EPB - 1) / EPB)   // 245
#define CAP  4096                // static per-bucket capacity (mean 3197, +15 sigma)
#define CAPPAD 1792              // extra capacity for pad-to-8 (256*7)
#define CAPP (CAP + CAPPAD)      // 5888: per-bucket stride in ssp
#define DUMMY N_NODES            // featW[DUMMY] is a zero row
#define HP 68                    // LDS leading-dim pad (16B-aligned float4 rows)

// ---------------- init: gcursor[b] = b*CAP ----------------
__global__ void init_kernel(int* __restrict__ gcursor) {
    int i = blockIdx.x * 256 + threadIdx.x;
    if (i < NB) gcursor[i] = i * CAP;
}

// ---------------- place: local counting sort, wave-shfl scan, ascending emission ----------------
__global__ __launch_bounds__(PTHREADS) void place_kernel(const int* __restrict__ src,
                                                         const int* __restrict__ dst,
                                                         int* __restrict__ gcursor,
                                                         unsigned int* __restrict__ packed) {
    __shared__ int h[512];
    __shared__ int wtot[4];
    __shared__ int lstart[NB];
    __shared__ int gbase[NB];
    __shared__ int lcur[NB];
    __shared__ unsigned sortedv[EPB];
    __shared__ unsigned short binof[EPB];
    int t = threadIdx.x;
    h[t] = 0;
    __syncthreads();

    int base = blockIdx.x * EPB;
    int d[EPT], s[EPT];
    #pragma unroll
    for (int i = 0; i < EPT; ++i) {
        int e = base + t + i * PTHREADS;
        if (e < N_EDGES) {
            d[i] = dst[e]; s[i] = src[e];
            atomicAdd(&h[d[i] >> 8], 1);
        } else d[i] = -1;
    }
    __syncthreads();

    // inclusive scan of pair-sums over t<256: 4 wave-local shfl scans + combine
    int a0 = 0, a1 = 0, x = 0;
    if (t < 256) {
        a0 = h[2 * t]; a1 = h[2 * t + 1];
        x = a0 + a1;
        int lane = t & 63;
        #pragma unroll
        for (int off = 1; off < 64; off <<= 1) {
            int y = __shfl_up(x, off, 64);
            if (lane >= off) x += y;
        }
        if (lane == 63) wtot[t >> 6] = x;
    }
    __syncthreads();
    if (t == 0) {
        int s0 = 0;
        #pragma unroll
        for (int i = 0; i < 4; ++i) { int v = wtot[i]; wtot[i] = s0; s0 += v; }
    }
    __syncthreads();
    if (t < 256) {
        int pinc = x + wtot[t >> 6];
        int pexc = pinc - a0 - a1;
        int b0 = 2 * t, b1 = 2 * t + 1;
        if (b0 < NB) {
            lstart[b0] = pexc;
            lcur[b0] = pexc;
            gbase[b0] = a0 ? atomicAdd(&gcursor[b0], a0) : 0;
        }
        if (b1 < NB) {
            lstart[b1] = pexc + a0;
            lcur[b1] = pexc + a0;
            gbase[b1] = a1 ? atomicAdd(&gcursor[b1], a1) : 0;
        }
    }
    __syncthreads();

    #pragma unroll
    for (int i = 0; i < EPT; ++i) {
        if (d[i] >= 0) {
            int b = d[i] >> 8;
            int pos = atomicAdd(&lcur[b], 1);
            sortedv[pos] = ((unsigned)s[i] << 8) | (unsigned)(d[i] & 255);
            binof[pos] = (unsigned short)b;
        }
    }
    __syncthreads();

    int cnt = min(EPB, N_EDGES - base);
    for (int k = t; k < cnt; k += PTHREADS) {
        int b = binof[k];
        int gp = gbase[b] + (k - lstart[b]);
        if (gp < (b + 1) * CAP) packed[gp] = sortedv[k];
    }
}

// ---------------- refine: padded CSR + norm (wave-shfl scan) ----------------
__global__ __launch_bounds__(1024) void refine_kernel(const unsigned int* __restrict__ packed,
                                                      const int* __restrict__ gcursor,
                                                      int* __restrict__ ssp,
                                                      int* __restrict__ pbeg,
                                                      int* __restrict__ pdega,
                                                      float* __restrict__ norm) {
    __shared__ int h[NPB];
    __shared__ int cur[NPB];
    __shared__ int wtot[4];
    int b = blockIdx.x, t = threadIdx.x;
    int beg = b * CAP;
    int end = min(gcursor[b], (b + 1) * CAP);
    if (t < NPB) h[t] = 0;
    __syncthreads();
    for (int j = beg + t; j < end; j += 1024)
        atomicAdd(&h[packed[j] & 255], 1);
    __syncthreads();

    int deg = 0, pdeg = 0, x = 0;
    if (t < NPB) {
        deg = h[t];
        pdeg = (deg + 7) & ~7;
        x = pdeg;
        int lane = t & 63;
        #pragma unroll
        for (int off = 1; off < 64; off <<= 1) {
            int y = __shfl_up(x, off, 64);
            if (lane >= off) x += y;
        }
        if (lane == 63) wtot[t >> 6] = x;
    }
    __syncthreads();
    if (t == 0) {
        int s0 = 0;
        #pragma unroll
        for (int i = 0; i < 4; ++i) { int v = wtot[i]; wtot[i] = s0; s0 += v; }
    }
    __syncthreads();
    int pb = 0;
    if (t < NPB) {
        int inc = x + wtot[t >> 6];
        int exc = inc - pdeg;
        pb = b * CAPP + exc;
        cur[t] = pb;
        int n = b * NPB + t;
        pbeg[n] = pb;
        pdega[n] = pdeg;
        norm[n] = rsqrtf((float)(deg < 1 ? 1 : deg));
    }
    __syncthreads();
    for (int j = beg + t; j < end; j += 1024) {
        unsigned p = packed[j];
        int pos = atomicAdd(&cur[p & 255], 1);
        ssp[pos] = (int)(p >> 8);
    }
    __syncthreads();
    if (t < NPB) {
        int fend = pb + pdeg;
        for (int k = cur[t]; k < fend; ++k) ssp[k] = DUMMY;
    }
}

// ---------------- featw: featW[n] = bf16(norm[n] * (feat[n] @ W^T)), zeros past N_NODES ----------------
__global__ __launch_bounds__(256) void featw_kernel(const float* __restrict__ feat,
                                                    const float* __restrict__ norm,
                                                    const float* __restrict__ weight,
                                                    unsigned short* __restrict__ featW) {
    __shared__ float Hcol[D * HP];   // Hcol[k][n_local] = feat[n][k]*norm[n]
    __shared__ float Wt[D * HP];     // Wt[k][d]
    int tid = threadIdx.x;
    int base = blockIdx.x * 64;

    #pragma unroll
    for (int i = tid; i < D * D; i += 256) {
        int c = i & 63, dd = i >> 6;
        Wt[c * HP + dd] = weight[dd * D + c];
    }
    #pragma unroll
    for (int idx = tid; idx < 64 * 16; idx += 256) {
        int nl = idx >> 4, q = idx & 15;
        int n = base + nl;
        float4 v = make_float4(0.f, 0.f, 0.f, 0.f);
        float nn = 0.f;
        if (n < N_NODES) {
            v = ((const float4*)feat)[(size_t)n * 16 + q];
            nn = norm[n];
        }
        Hcol[(q * 4 + 0) * HP + nl] = v.x * nn;
        Hcol[(q * 4 + 1) * HP + nl] = v.y * nn;
        Hcol[(q * 4 + 2) * HP + nl] = v.z * nn;
        Hcol[(q * 4 + 3) * HP + nl] = v.w * nn;
    }
    __syncthreads();

    int tx = tid & 15, ty = tid >> 4;
    float acc[4][4] = {};
    #pragma unroll 8
    for (int k = 0; k < D; ++k) {
        float4 a = *(const float4*)&Hcol[k * HP + ty * 4];
        float4 b = *(const float4*)&Wt[k * HP + tx * 4];
        acc[0][0] += a.x * b.x; acc[0][1] += a.x * b.y; acc[0][2] += a.x * b.z; acc[0][3] += a.x * b.w;
        acc[1][0] += a.y * b.x; acc[1][1] += a.y * b.y; acc[1][2] += a.y * b.z; acc[1][3] += a.y * b.w;
        acc[2][0] += a.z * b.x; acc[2][1] += a.z * b.y; acc[2][2] += a.z * b.z; acc[2][3] += a.z * b.w;
        acc[3][0] += a.w * b.x; acc[3][1] += a.w * b.y; acc[3][2] += a.w * b.z; acc[3][3] += a.w * b.w;
    }
    auto cvt = [](float x) -> unsigned {
        unsigned u = __float_as_uint(x);
        return (u + 0x7fff + ((u >> 16) & 1)) >> 16;
    };
    #pragma unroll
    for (int i = 0; i < 4; ++i) {
        int n = base + ty * 4 + i;    // always < NPAD2; rows >= N_NODES get exact zeros
        uint2 r;
        r.x = cvt(acc[i][0]) | (cvt(acc[i][1]) << 16);
        r.y = cvt(acc[i][2]) | (cvt(acc[i][3]) << 16);
        *(uint2*)&featW[(size_t)n * D + tx * 4] = r;
    }
}

// ---------------- gather_out: pure CSR gather -> *norm[dst] + bias -> out (r7 2-pair form) ----------------
#define ACC_EDGE(ACC, J) do {                                         \
        int s_ = ssp[(J)];                                            \
        uint2 r_ = *(const uint2*)&featW[(size_t)s_ * D + m * 4];     \
        ACC.x += __uint_as_float(r_.x << 16);                         \
        ACC.y += __uint_as_float(r_.x & 0xffff0000u);                 \
        ACC.z += __uint_as_float(r_.y << 16);                         \
        ACC.w += __uint_as_float(r_.y & 0xffff0000u);                 \
    } while (0)
#define ACC4(ACC, J) { ACC_EDGE(ACC, (J) + q); ACC_EDGE(ACC, (J) + 4 + q); \
                       ACC_EDGE(ACC, (J) + 8 + q); ACC_EDGE(ACC, (J) + 12 + q); }
#define ACC2(ACC, J) { ACC_EDGE(ACC, (J) + q); ACC_EDGE(ACC, (J) + 4 + q); }

__global__ __launch_bounds__(512) void gather_out_kernel(const unsigned short* __restrict__ featW,
                                                         const int* __restrict__ ssp,
                                                         const int* __restrict__ pbeg,
                                                         const int* __restrict__ pdega,
                                                         const float* __restrict__ norm,
                                                         const float* __restrict__ bias,
                                                         float* __restrict__ out) {
    int tid = threadIdx.x;
    int base = blockIdx.x * 32;          // 8 waves x 4 nodes
    int w = tid >> 6;
    int lane = tid & 63;
    int q = lane >> 4, m = lane & 15;
    float4 bv = ((const float4*)bias)[m];

    #pragma unroll
    for (int pr = 0; pr < 2; ++pr) {
        int nA = base + w * 4 + pr * 2;
        int nB = nA + 1;
        int begA = pbeg[nA], endA = begA + pdega[nA];
        int begB = pbeg[nB], endB = begB + pdega[nB];
        float4 aA = make_float4(0.f, 0.f, 0.f, 0.f);
        float4 aB = make_float4(0.f, 0.f, 0.f, 0.f);
        int jA = begA, jB = begB;
        while (jA + 16 <= endA && jB + 16 <= endB) {   // 8 row-loads in flight
            ACC4(aA, jA); ACC4(aB, jB);
            jA += 16; jB += 16;
        }
        for (; jA + 16 <= endA; jA += 16) ACC4(aA, jA);
        for (; jB + 16 <= endB; jB += 16) ACC4(aB, jB);
        if (jA < endA) ACC2(aA, jA);                    // exactly 8 remain
        if (jB < endB) ACC2(aB, jB);

        #pragma unroll
        for (int mask = 16; mask <= 32; mask <<= 1) {
            aA.x += __shfl_xor(aA.x, mask); aA.y += __shfl_xor(aA.y, mask);
            aA.z += __shfl_xor(aA.z, mask); aA.w += __shfl_xor(aA.w, mask);
            aB.x += __shfl_xor(aB.x, mask); aB.y += __shfl_xor(aB.y, mask);
            aB.z += __shfl_xor(aB.z, mask); aB.w += __shfl_xor(aB.w, mask);
        }
        float nnA = norm[nA], nnB = norm[nB];
        if (q == 0 && nA < N_NODES) {
            *(float4*)&out[(size_t)nA * D + m * 4] =
                make_float4(aA.x * nnA + bv.x, aA.y * nnA + bv.y,
                            aA.z * nnA + bv.z, aA.w * nnA + bv.w);
        }
        if (q == 1 && nB < N_NODES) {
            *(float4*)&out[(size_t)nB * D + m * 4] =
                make_float4(aB.x * nnB + bv.x, aB.y * nnB + bv.y,
                            aB.z * nnB + bv.z, aB.w * nnB + bv.w);
        }
    }
}

extern "C" void kernel_launch(void* const* d_in, const int* in_sizes, int n_in,
                              void* d_out, int out_size, void* d_ws, size_t ws_size,
                              hipStream_t stream) {
    const float* feat   = (const float*)d_in[0];
    const int*   src    = (const int*)d_in[1];
    const int*   dst    = (const int*)d_in[2];
    const float* weight = (const float*)d_in[3];
    const float* bias   = (const float*)d_in[4];
    float* out = (float*)d_out;

    // workspace layout (4-byte units); high water ~30 MB
    int* w = (int*)d_ws;
    int*      gcursor = w;                                   // [NB]
    int*      pbeg    = gcursor + NB;                        // [NPAD2]
    int*      pdega   = pbeg + NPAD2;                        // [NPAD2]
    float*    norm    = (float*)(pdega + NPAD2);             // [NPAD2]
    int*      ssp     = (int*)(norm + NPAD2);                // [NB*CAPP]
    unsigned* packed  = (unsigned*)(ssp + (size_t)NB * CAPP);// [NB*CAP]
    size_t featW_off = (size_t)NB + 3 * (size_t)NPAD2 + (size_t)NB * CAPP + (size_t)NB * CAP;
    featW_off = (featW_off + 3) & ~(size_t)3;                // 16B-align
    unsigned short* featW = (unsigned short*)(w + featW_off);// [NPAD2*D] bf16

    init_kernel      <<<2, 256, 0, stream>>>(gcursor);
    place_kernel     <<<NBLK, PTHREADS, 0, stream>>>(src, dst, gcursor, packed);
    refine_kernel    <<<NB, 1024, 0, stream>>>(packed, gcursor, ssp, pbeg, pdega, norm);
    featw_kernel     <<<(NPAD2 + 63) / 64, 256, 0, stream>>>(feat, norm, weight, featW);
    gather_out_kernel<<<(NPAD2 + 31) / 32, 512, 0, stream>>>(featW, ssp, pbeg, pdega, norm,
                                                             bias, out);
}